// Round 11
// baseline (2529.286 us; speedup 1.0000x reference)
//
#include <hip/hip_runtime.h>

#define BATCHN 128
#define SEQT   2048
#define FEAT   64
#define UNITS  64
#define NCOL   256   // 4*UNITS gate columns
#define OUTD   6
#define CH     24    // chunk stride in floats (16 data + 8 pad)
#define SLOT   128   // floats per h ring slot (power of 2 -> shift addressing)
#define XRING  8     // x ring slots
#define PFD    4     // x prefetch distance (ticks)

typedef float v2f __attribute__((ext_vector_type(2)));

__device__ __forceinline__ float fast_exp2(float x) {
#if __has_builtin(__builtin_amdgcn_exp2f)
    return __builtin_amdgcn_exp2f(x);
#else
    return exp2f(x);
#endif
}
__device__ __forceinline__ float fast_rcp(float x) {
#if __has_builtin(__builtin_amdgcn_rcpf)
    return __builtin_amdgcn_rcpf(x);
#else
    return 1.0f / x;
#endif
}
__device__ __forceinline__ float sig_(float x) {
    return fast_rcp(1.0f + fast_exp2(-1.4426950408889634f * x));
}
__device__ __forceinline__ float tanh_(float x) {
    float xc = fminf(fmaxf(x, -15.0f), 15.0f);
    float e  = fast_exp2(2.8853900817779268f * xc);  // e^(2x)
    return (e - 1.0f) * fast_rcp(e + 1.0f);
}

__device__ __forceinline__ v2f pk_fma(v2f a, v2f b, v2f c) {
    return __builtin_elementwise_fma(a, b, c);
}

template<int CTRL>
__device__ __forceinline__ float dppf(float v) {
    return __builtin_bit_cast(float, __builtin_amdgcn_update_dpp(
        0, __builtin_bit_cast(int, v), CTRL, 0xF, 0xF, true));
}
// reduce both v2f components across 8 consecutive lanes (bits [2:0])
__device__ __forceinline__ v2f red8v(v2f v) {
    v2f t;
    t.x = dppf<0xB1>(v.x);  t.y = dppf<0xB1>(v.y);  v = v + t;  // xor 1
    t.x = dppf<0x4E>(v.x);  t.y = dppf<0x4E>(v.y);  v = v + t;  // xor 2
    t.x = dppf<0x141>(v.x); t.y = dppf<0x141>(v.y); v = v + t;  // xor 4 (RHM)
    return v;
}

// async global->LDS DMA, 16B per active lane; LDS dest = uniform base + lane*16
__device__ __forceinline__ void gload16(float* lds, const float* g) {
    __builtin_amdgcn_global_load_lds(
        (const __attribute__((address_space(1))) void*)g,
        (__attribute__((address_space(3))) void*)lds, 16, 0, 0);
}

__device__ __forceinline__ int ldflag(const int* p) {
    return __hip_atomic_load(p, __ATOMIC_RELAXED, __HIP_MEMORY_SCOPE_WORKGROUP);
}

__global__ __launch_bounds__(768, 3)
void lstm3_df(const float* __restrict__ x,
              const float* __restrict__ W0, const float* __restrict__ U0,
              const float* __restrict__ b0,
              const float* __restrict__ W1, const float* __restrict__ U1,
              const float* __restrict__ b1,
              const float* __restrict__ Wf, const float* __restrict__ bfv,
              const float* __restrict__ Wo, const float* __restrict__ bov,
              float* __restrict__ out)
{
    const int b   = blockIdx.x;
    const int tid = threadIdx.x;   // 0..767
    const int grp = tid >> 8;      // layer group 0,1,2
    const int lt  = tid & 255;     // lane within group
    const int cg  = lt >> 3;       // col-group 0..31 (2 units x 4 gates)
    const int kg  = lt & 7;        // k-group (0-3 FF, 4-7 REC)
    const int up  = kg & 1;
    const int myu = 2 * cg + up;
    const int wv  = tid >> 6;      // wave id 0..11 (wave 0 stages x)

    __shared__ __align__(16) float lh[3 * 4 * SLOT];   // h rings, 4 slots/group
    __shared__ __align__(16) float lxr[XRING * FEAT];  // x ring
    __shared__ float lact[UNITS];
    __shared__ int prog[4];        // [g]=last step completed by group g; [3]=xprog
    __shared__ int cnt[3][2];      // per-group completion counters, by step parity

    // ---- weights: 8 cols x 16 k per lane (R7 layout, 128 f32) ----
    const float* Wsel = (grp == 0) ? W0 : W1;
    const float* Usel = (grp == 0) ? U0 : U1;
    const float* bsel = (grp == 0) ? b0 : b1;
    const float* Msel = (kg < 4) ? Wsel : Usel;

    v2f wt[16][4];
    float biasv[4];
#pragma unroll
    for (int g = 0; g < 4; ++g) {
        const int colb = (g << 6) + 2 * cg;
#pragma unroll
        for (int k = 0; k < 16; ++k) {
            const int r = (kg & 3) * 16 + k;
            wt[k][g] = (v2f){Msel[r * NCOL + colb], Msel[r * NCOL + colb + 1]};
        }
        biasv[g] = bsel[(g << 6) + myu];
    }

    // zero h rings + flags
    for (int i = tid; i < 3 * 4 * SLOT; i += 768) lh[i] = 0.f;
    if (tid < 4) prog[tid] = -1;
    if (tid < 6) (&cnt[0][0])[tid] = 0;

    // x prologue: slots 0..PFD-1 in flight
    const float* xbase = x + (size_t)b * SEQT * FEAT;
    if (tid < 16) {
#pragma unroll
        for (int s = 0; s < PFD; ++s)
            gload16(&lxr[s * FEAT], xbase + (size_t)s * FEAT + tid * 4);
    }
    __syncthreads();   // one-time full drain

    // lane-constant operand bases
    const bool isFF = (kg < 4);
    const bool xOp  = (grp == 0) && isFF;
    const float* opB = isFF
        ? ((grp == 0) ? (const float*)lxr
                      : (&lh[(grp - 1) * 4 * SLOT] + (kg & 3) * CH))
        : (&lh[grp * 4 * SLOT] + (kg & 3) * CH);
    float* const hgrp = &lh[grp * 4 * SLOT];
    const int hwoff = CH * (myu >> 4) + (myu & 15);

    float c = 0.f;

#pragma unroll 1
    for (int t = 0; t < SEQT; ++t) {
        const int sW = t & 3, sR = (t + 3) & 3, sX = t & 7;

        // ---- dataflow sync: FF producer / own-group REC / backpressure / x --
        for (;;) {
            bool ok = (ldflag(&prog[grp]) >= t - 1);                    // REC
            if (grp > 0) ok = ok && (ldflag(&prog[grp - 1]) >= t);      // FF
            if (grp < 2) ok = ok && (ldflag(&prog[grp + 1]) >= t - 4);  // BP
            if (grp == 0 && wv != 0) ok = ok && (ldflag(&prog[3]) >= t);// x
            if (ok) break;
            __builtin_amdgcn_s_sleep(1);
        }
        asm volatile("" ::: "memory");   // compiler fence; DS is in-order per wave

        // ---- x staging (wave 0 only): issue x(t+PFD), counted vmcnt ----
        if (wv == 0) {
            if (t + PFD < SEQT) {
                if (tid < 16)
                    gload16(&lxr[((t + PFD) & 7) * FEAT],
                            xbase + (size_t)(t + PFD) * FEAT + tid * 4);
                asm volatile("s_waitcnt vmcnt(4)" ::: "memory");  // x(t) landed
            } else if (t == SEQT - 4) { asm volatile("s_waitcnt vmcnt(3)" ::: "memory"); }
            else if   (t == SEQT - 3) { asm volatile("s_waitcnt vmcnt(2)" ::: "memory"); }
            else if   (t == SEQT - 2) { asm volatile("s_waitcnt vmcnt(1)" ::: "memory"); }
            else                      { asm volatile("s_waitcnt vmcnt(0)" ::: "memory"); }
            if (tid == 0)
                __hip_atomic_store(&prog[3], t, __ATOMIC_RELAXED,
                                   __HIP_MEMORY_SCOPE_WORKGROUP);
        }

        // ---- cell compute (R7 body) ----
        const float* op = xOp ? (lxr + sX * FEAT + kg * 16)
                              : (opB + (isFF ? sW : sR) * SLOT);
        float4 o0 = *(const float4*)(op);
        float4 o1 = *(const float4*)(op + 4);
        float4 o2 = *(const float4*)(op + 8);
        float4 o3 = *(const float4*)(op + 12);

        v2f a0 = (v2f){0.f, 0.f}, a1 = a0, a2 = a0, a3 = a0;
#define MAC1(V, K)                                                            \
        { v2f s_; s_.x = (V); s_.y = (V);                                     \
          a0 = pk_fma(s_, wt[K][0], a0);                                      \
          a1 = pk_fma(s_, wt[K][1], a1);                                      \
          a2 = pk_fma(s_, wt[K][2], a2);                                      \
          a3 = pk_fma(s_, wt[K][3], a3); }
        MAC1(o0.x, 0)  MAC1(o0.y, 1)  MAC1(o0.z, 2)  MAC1(o0.w, 3)
        MAC1(o1.x, 4)  MAC1(o1.y, 5)  MAC1(o1.z, 6)  MAC1(o1.w, 7)
        MAC1(o2.x, 8)  MAC1(o2.y, 9)  MAC1(o2.z, 10) MAC1(o2.w, 11)
        MAC1(o3.x, 12) MAC1(o3.y, 13) MAC1(o3.z, 14) MAC1(o3.w, 15)
#undef MAC1

        v2f z0 = red8v(a0), z1 = red8v(a1), z2 = red8v(a2), z3 = red8v(a3);
        const float zi = (up ? z0.y : z0.x) + biasv[0];
        const float zf = (up ? z1.y : z1.x) + biasv[1];
        const float zg = (up ? z2.y : z2.x) + biasv[2];
        const float zo = (up ? z3.y : z3.x) + biasv[3];

        const float ig = sig_(zi), fg = sig_(zf);
        const float gg = tanh_(zg), og = sig_(zo);
        c = fg * c + ig * gg;
        const float hn = og * tanh_(c);
        if (kg < 2) hgrp[sW * SLOT + hwoff] = hn;

        // ---- completion: 4th wave of the group publishes prog[grp] = t ----
        asm volatile("" ::: "memory");   // keep h-write before counter (DS in-order)
        if ((lt & 63) == 0) {
            int old = __hip_atomic_fetch_add(&cnt[grp][t & 1], 1,
                        __ATOMIC_RELAXED, __HIP_MEMORY_SCOPE_WORKGROUP);
            if (old == 3) {
                __hip_atomic_store(&cnt[grp][t & 1], 0, __ATOMIC_RELAXED,
                                   __HIP_MEMORY_SCOPE_WORKGROUP);
                __hip_atomic_store(&prog[grp], t, __ATOMIC_RELAXED,
                                   __HIP_MEMORY_SCOPE_WORKGROUP);
            }
        }
    }

    __syncthreads();

    // ---- dense head on final h2 (step SEQT-1 -> slot 3, chunked) ----
    const float* h2f = &lh[(2 * 4 + 3) * SLOT];
    if (tid < UNITS) {
        float a = bfv[tid];
#pragma unroll
        for (int k = 0; k < UNITS; ++k)
            a += h2f[CH * (k >> 4) + (k & 15)] * Wf[k * 64 + tid];
        lact[tid] = fmaxf(a, 0.f);
    }
    __syncthreads();
    if (tid < OUTD) {
        float a = bov[tid];
#pragma unroll
        for (int k = 0; k < UNITS; ++k) a += lact[k] * Wo[k * OUTD + tid];
        out[b * OUTD + tid] = a;
    }
}

extern "C" void kernel_launch(void* const* d_in, const int* in_sizes, int n_in,
                              void* d_out, int out_size, void* d_ws, size_t ws_size,
                              hipStream_t stream) {
    const float* x   = (const float*)d_in[0];
    const float* W0  = (const float*)d_in[1];
    const float* U0  = (const float*)d_in[2];
    const float* b0  = (const float*)d_in[3];
    const float* W1  = (const float*)d_in[4];
    const float* U1  = (const float*)d_in[5];
    const float* b1  = (const float*)d_in[6];
    const float* Wf  = (const float*)d_in[7];
    const float* bfv = (const float*)d_in[8];
    const float* Wo  = (const float*)d_in[9];
    const float* bov = (const float*)d_in[10];
    float* out = (float*)d_out;

    lstm3_df<<<BATCHN, 768, 0, stream>>>(x, W0, U0, b0, W1, U1, b1,
                                         Wf, bfv, Wo, bov, out);
}

// Round 13
// 1996.406 us; speedup vs baseline: 1.2669x; 1.2669x over previous
//
#include <hip/hip_runtime.h>

#define BATCHN 128
#define SEQT   2048
#define FEAT   64
#define UNITS  64
#define NCOL   256   // 4*UNITS gate columns
#define OUTD   6
#define RING   8     // x ring slots (f32)
#define PFD    6     // x prefetch distance (ticks)
#define CHB    48    // bytes per h chunk (16 units = 8 f16x2 pairs = 32B data + 16B pad)
#define HBUF   192   // bytes per h buffer (4 chunks)

typedef float v2f __attribute__((ext_vector_type(2)));
typedef __fp16 hv2 __attribute__((ext_vector_type(2)));   // matches cvt_pkrtz/fdot2

__device__ __forceinline__ float fast_exp2(float x) {
#if __has_builtin(__builtin_amdgcn_exp2f)
    return __builtin_amdgcn_exp2f(x);
#else
    return exp2f(x);
#endif
}
__device__ __forceinline__ float fast_rcp(float x) {
#if __has_builtin(__builtin_amdgcn_rcpf)
    return __builtin_amdgcn_rcpf(x);
#else
    return 1.0f / x;
#endif
}
__device__ __forceinline__ float sig_(float x) {
    return fast_rcp(1.0f + fast_exp2(-1.4426950408889634f * x));
}
// tanh(x) = 2/(1+e^{-2x}) - 1
__device__ __forceinline__ float tanh_(float x) {
    float e = fast_exp2(-2.8853900817779268f * x);   // e^{-2x}
    return fmaf(2.0f, fast_rcp(1.0f + e), -1.0f);
}

// 2xf16 MAC with f32 accumulate: D = a.x*b.x + a.y*b.y + c  (v_dot2_f32_f16)
__device__ __forceinline__ float fdot2_(hv2 a, hv2 b, float c) {
#if __has_builtin(__builtin_amdgcn_fdot2)
    return __builtin_amdgcn_fdot2(a, b, c, false);
#else
    return fmaf((float)a.x, (float)b.x, fmaf((float)a.y, (float)b.y, c));
#endif
}

__device__ __forceinline__ hv2 cvtpk_(float a, float b) {
    return __builtin_amdgcn_cvt_pkrtz(a, b);
}

template<int CTRL>
__device__ __forceinline__ float dppf(float v) {
    return __builtin_bit_cast(float, __builtin_amdgcn_update_dpp(
        0, __builtin_bit_cast(int, v), CTRL, 0xF, 0xF, true));
}
// reduce both v2f components across 8 consecutive lanes (bits [2:0])
__device__ __forceinline__ v2f red8v(v2f v) {
    v2f t;
    t.x = dppf<0xB1>(v.x);  t.y = dppf<0xB1>(v.y);  v = v + t;  // xor 1
    t.x = dppf<0x4E>(v.x);  t.y = dppf<0x4E>(v.y);  v = v + t;  // xor 2
    t.x = dppf<0x141>(v.x); t.y = dppf<0x141>(v.y); v = v + t;  // xor 4 (RHM)
    return v;
}

// async global->LDS DMA, 16B per active lane
__device__ __forceinline__ void gload16(float* lds, const float* g) {
    __builtin_amdgcn_global_load_lds(
        (const __attribute__((address_space(1))) void*)g,
        (__attribute__((address_space(3))) void*)lds, 16, 0, 0);
}

__global__ __launch_bounds__(768, 3)
void lstm3_h16(const float* __restrict__ x,
               const float* __restrict__ W0, const float* __restrict__ U0,
               const float* __restrict__ b0,
               const float* __restrict__ W1, const float* __restrict__ U1,
               const float* __restrict__ b1,
               const float* __restrict__ Wf, const float* __restrict__ bfv,
               const float* __restrict__ Wo, const float* __restrict__ bov,
               float* __restrict__ out)
{
    const int b   = blockIdx.x;
    const int tid = threadIdx.x;   // 0..767
    const int grp = tid >> 8;      // pipeline stage 0,1,2 (layer)
    const int lt  = tid & 255;     // 0..255 within group
    const int cg  = lt >> 3;       // col-group 0..31 (2 units x 4 gates)
    const int kg  = lt & 7;        // k-group (0-3 FF, 4-7 REC), 16 k each
    const int up  = kg & 1;        // unit parity this lane activates
    const int myu = 2 * cg + up;
    const int wv  = tid >> 6;      // wave id (wave 0 stages x)

    // LDS: h buffers f16x2-packed, [grp*2+parity]; x ring f32
    __shared__ __align__(16) unsigned char lhb[6 * HBUF];
    __shared__ __align__(16) float lxr[RING * FEAT];
    __shared__ float lact[UNITS];

    // ---- weights: 8 cols x 16 k as f16 k-pairs: wt[gate][e][j] (64 VGPRs) ----
    const float* Wsel = (grp == 0) ? W0 : W1;
    const float* Usel = (grp == 0) ? U0 : U1;
    const float* bsel = (grp == 0) ? b0 : b1;
    const float* Msel = (kg < 4) ? Wsel : Usel;

    hv2 wt[4][2][8];
    float biasv[4];
#pragma unroll
    for (int g = 0; g < 4; ++g) {
        const int colb = (g << 6) + 2 * cg;
#pragma unroll
        for (int j = 0; j < 8; ++j) {
            const int r = (kg & 3) * 16 + 2 * j;
            hv2 w0p, w1p;                       // RTN casts (init-time only)
            w0p.x = (__fp16)Msel[r * NCOL + colb];
            w0p.y = (__fp16)Msel[(r + 1) * NCOL + colb];
            w1p.x = (__fp16)Msel[r * NCOL + colb + 1];
            w1p.y = (__fp16)Msel[(r + 1) * NCOL + colb + 1];
            wt[g][0][j] = w0p;
            wt[g][1][j] = w1p;
        }
        biasv[g] = bsel[(g << 6) + myu];
    }

    // zero h buffers (h(-1)=0 both parities)
    if (tid < 6 * HBUF / 4) ((unsigned int*)lhb)[tid] = 0u;

    // x ring prologue: DMA x(0..PFD-1)
    const float* xbase = x + (size_t)b * SEQT * FEAT;
    if (tid < 16) {
#pragma unroll
        for (int s = 0; s < PFD; ++s)
            gload16(&lxr[s * FEAT], xbase + (size_t)s * FEAT + tid * 4);
    }
    __syncthreads();   // one-time full drain

    // operand pointers (f16 buffers), both parities; read parity = p^1
    const bool isFF = (kg < 4);
    const bool xOp  = (grp == 0) && isFF;
    const int ffb   = (grp == 0) ? 0 : (grp - 1);
    const unsigned char* opP0 =
        lhb + ((isFF ? ffb : grp) * 2 + 0) * HBUF + (kg & 3) * CHB;
    const unsigned char* opP1 = opP0 + HBUF;

    // h write pointers (lane kg==0 writes pair cg), write parity = p
    unsigned char* hwP0 = lhb + (grp * 2 + 0) * HBUF + (cg >> 3) * CHB + (cg & 7) * 4;
    unsigned char* hwP1 = hwP0 + HBUF;

    float c = 0.f;

    for (int tk = 0; tk < SEQT + 2; ++tk) {
        const int p = tk & 1;

        // ---- x staging (wave 0): DMA x(tk+PFD); counted vmcnt, never 0 mid-loop
        if (wv == 0) {
            if (tk + PFD < SEQT) {
                if (tid < 16)
                    gload16(&lxr[((tk + PFD) & (RING - 1)) * FEAT],
                            xbase + (size_t)(tk + PFD) * FEAT + tid * 4);
                asm volatile("s_waitcnt vmcnt(5)" ::: "memory");
            }
            else if (tk == SEQT - 6) { asm volatile("s_waitcnt vmcnt(4)" ::: "memory"); }
            else if (tk == SEQT - 5) { asm volatile("s_waitcnt vmcnt(3)" ::: "memory"); }
            else if (tk == SEQT - 4) { asm volatile("s_waitcnt vmcnt(2)" ::: "memory"); }
            else if (tk == SEQT - 3) { asm volatile("s_waitcnt vmcnt(1)" ::: "memory"); }
            else                     { asm volatile("s_waitcnt vmcnt(0)" ::: "memory"); }
        }

        const int t_ = tk - grp;
        if (t_ >= 0 && t_ < SEQT) {
            // ---- operand: 8 f16 pairs ----
            hv2 op[8];
            if (xOp) {   // G0-FF: f32 x from ring, convert
                const float* xp = lxr + (tk & (RING - 1)) * FEAT + (kg & 3) * 16;
                float4 q0 = *(const float4*)(xp);
                float4 q1 = *(const float4*)(xp + 4);
                float4 q2 = *(const float4*)(xp + 8);
                float4 q3 = *(const float4*)(xp + 12);
                op[0] = cvtpk_(q0.x, q0.y);
                op[1] = cvtpk_(q0.z, q0.w);
                op[2] = cvtpk_(q1.x, q1.y);
                op[3] = cvtpk_(q1.z, q1.w);
                op[4] = cvtpk_(q2.x, q2.y);
                op[5] = cvtpk_(q2.z, q2.w);
                op[6] = cvtpk_(q3.x, q3.y);
                op[7] = cvtpk_(q3.z, q3.w);
            } else {     // f16 h: 32B = 2 x b128, pure broadcast (conflict-free)
                const unsigned char* ob = p ? opP0 : opP1;   // parity p^1
                uint4 r0 = *(const uint4*)(ob);
                uint4 r1 = *(const uint4*)(ob + 16);
                op[0] = __builtin_bit_cast(hv2, r0.x);
                op[1] = __builtin_bit_cast(hv2, r0.y);
                op[2] = __builtin_bit_cast(hv2, r0.z);
                op[3] = __builtin_bit_cast(hv2, r0.w);
                op[4] = __builtin_bit_cast(hv2, r1.x);
                op[5] = __builtin_bit_cast(hv2, r1.y);
                op[6] = __builtin_bit_cast(hv2, r1.z);
                op[7] = __builtin_bit_cast(hv2, r1.w);
            }

            // ---- 64 x v_dot2_f32_f16 (128 MACs), 8 independent f32 acc chains
            float acc[4][2];
#pragma unroll
            for (int g = 0; g < 4; ++g) { acc[g][0] = 0.f; acc[g][1] = 0.f; }
#pragma unroll
            for (int j = 0; j < 8; ++j) {
#pragma unroll
                for (int g = 0; g < 4; ++g) {
                    acc[g][0] = fdot2_(op[j], wt[g][0][j], acc[g][0]);
                    acc[g][1] = fdot2_(op[j], wt[g][1][j], acc[g][1]);
                }
            }

            // ---- cross-lane reduce over the 8-lane kg group ----
            v2f z0, z1, z2, z3;
            z0.x = acc[0][0]; z0.y = acc[0][1];
            z1.x = acc[1][0]; z1.y = acc[1][1];
            z2.x = acc[2][0]; z2.y = acc[2][1];
            z3.x = acc[3][0]; z3.y = acc[3][1];
            z0 = red8v(z0); z1 = red8v(z1); z2 = red8v(z2); z3 = red8v(z3);

            const float zi = (up ? z0.y : z0.x) + biasv[0];
            const float zf = (up ? z1.y : z1.x) + biasv[1];
            const float zg = (up ? z2.y : z2.x) + biasv[2];
            const float zo = (up ? z3.y : z3.x) + biasv[3];

            const float ig = sig_(zi), fg = sig_(zf);
            const float gg = tanh_(zg), og = sig_(zo);
            c = fg * c + ig * gg;
            const float hn = og * tanh_(c);

            // pack (h[2cg], h[2cg+1]) as f16x2: kg0 pulls kg1's hn via quad DPP
            const float hother = dppf<0xF5>(hn);   // quad_perm [1,1,3,3]
            if (kg == 0) {
                hv2 hp = cvtpk_(hn, hother);
                *(unsigned int*)(p ? hwP1 : hwP0) =
                    __builtin_bit_cast(unsigned int, hp);
            }
        }

        // LDS-only drain + barrier (x DMAs stay in flight)
        asm volatile("s_waitcnt lgkmcnt(0)\n\ts_barrier" ::: "memory");
    }

    // ---- dense head on final h2 (buffer grp2/parity1, f16) ----
    const __fp16* h2f = (const __fp16*)(lhb + 5 * HBUF);
    if (tid < UNITS) {
        float a = bfv[tid];
#pragma unroll
        for (int k = 0; k < UNITS; ++k)
            a += (float)h2f[(k >> 4) * 24 + (k & 15)] * Wf[k * 64 + tid];
        lact[tid] = fmaxf(a, 0.f);
    }
    __syncthreads();
    if (tid < OUTD) {
        float a = bov[tid];
#pragma unroll
        for (int k = 0; k < UNITS; ++k) a += lact[k] * Wo[k * OUTD + tid];
        out[b * OUTD + tid] = a;
    }
}

extern "C" void kernel_launch(void* const* d_in, const int* in_sizes, int n_in,
                              void* d_out, int out_size, void* d_ws, size_t ws_size,
                              hipStream_t stream) {
    const float* x   = (const float*)d_in[0];
    const float* W0  = (const float*)d_in[1];
    const float* U0  = (const float*)d_in[2];
    const float* b0  = (const float*)d_in[3];
    const float* W1  = (const float*)d_in[4];
    const float* U1  = (const float*)d_in[5];
    const float* b1  = (const float*)d_in[6];
    const float* Wf  = (const float*)d_in[7];
    const float* bfv = (const float*)d_in[8];
    const float* Wo  = (const float*)d_in[9];
    const float* bov = (const float*)d_in[10];
    float* out = (float*)d_out;

    lstm3_h16<<<BATCHN, 768, 0, stream>>>(x, W0, U0, b0, W1, U1, b1,
                                          Wf, bfv, Wo, bov, out);
}

// Round 14
// 1925.489 us; speedup vs baseline: 1.3136x; 1.0368x over previous
//
#include <hip/hip_runtime.h>

#define BATCHN 128
#define SEQT   2048
#define FEAT   64
#define UNITS  64
#define NCOL   256   // 4*UNITS gate columns
#define OUTD   6

typedef __fp16 hv2 __attribute__((ext_vector_type(2)));

__device__ __forceinline__ float fast_exp2(float x) {
#if __has_builtin(__builtin_amdgcn_exp2f)
    return __builtin_amdgcn_exp2f(x);
#else
    return exp2f(x);
#endif
}
__device__ __forceinline__ float fast_rcp(float x) {
#if __has_builtin(__builtin_amdgcn_rcpf)
    return __builtin_amdgcn_rcpf(x);
#else
    return 1.0f / x;
#endif
}
__device__ __forceinline__ float sig_(float x) {
    return fast_rcp(1.0f + fast_exp2(-1.4426950408889634f * x));
}
// tanh(x) = 2/(1+e^{-2x}) - 1
__device__ __forceinline__ float tanh_(float x) {
    float e = fast_exp2(-2.8853900817779268f * x);   // e^{-2x}
    return fmaf(2.0f, fast_rcp(1.0f + e), -1.0f);
}

// 2xf16 MAC with f32 accumulate (v_dot2_f32_f16)
__device__ __forceinline__ float fdot2_(hv2 a, hv2 b, float c) {
#if __has_builtin(__builtin_amdgcn_fdot2)
    return __builtin_amdgcn_fdot2(a, b, c, false);
#else
    return fmaf((float)a.x, (float)b.x, fmaf((float)a.y, (float)b.y, c));
#endif
}
__device__ __forceinline__ hv2 cvtpk_(float a, float b) {
    return __builtin_amdgcn_cvt_pkrtz(a, b);
}
// wave-uniform broadcast of lane l's u32 (compile-time l)
__device__ __forceinline__ unsigned int rlane_(unsigned int v, int l) {
    return (unsigned int)__builtin_amdgcn_readlane((int)v, l);
}
// pull f32 from lane (byteaddr/4)
__device__ __forceinline__ float bperm_(int byteaddr, float v) {
    return __builtin_bit_cast(float,
        __builtin_amdgcn_ds_bpermute(byteaddr, __builtin_bit_cast(int, v)));
}

// 3 waves, one per layer, one per SIMD. Lane u = unit u's 4 gate cols over
// full K=64: dot completes in-lane (no reduce). Broadcast via v_readlane of
// packed f16x2 pairs. REC h repacked in-register (2x ds_bpermute + cvt_pkrtz).
// FF handoff: 32 packed u32 through LDS, double-buffered by tick parity.
__global__ __launch_bounds__(192, 1)
void lstm3_w3(const float* __restrict__ x,
              const float* __restrict__ W0, const float* __restrict__ U0,
              const float* __restrict__ b0,
              const float* __restrict__ W1, const float* __restrict__ U1,
              const float* __restrict__ b1,
              const float* __restrict__ Wf, const float* __restrict__ bfv,
              const float* __restrict__ Wo, const float* __restrict__ bov,
              float* __restrict__ out)
{
    const int b   = blockIdx.x;
    const int tid = threadIdx.x;   // 0..191
    const int g   = tid >> 6;      // layer/wave 0..2
    const int u   = tid & 63;      // unit/lane
    const int j32 = u & 31;

    __shared__ unsigned int lhp[3][2][32];  // packed h pairs [layer][parity]
    __shared__ float lh2f[UNITS];           // final h2, f32
    __shared__ float lact[UNITS];

    // ---- weights: 4 cols x 64 k of W and U, f16 k-pairs (256 VGPRs) ----
    const float* Wsel = (g == 0) ? W0 : W1;
    const float* Usel = (g == 0) ? U0 : U1;
    const float* bsel = (g == 0) ? b0 : b1;

    hv2 wF[32][4], wR[32][4];
    float biasv[4];
#pragma unroll
    for (int gg = 0; gg < 4; ++gg) {
        const int col = (gg << 6) + u;
#pragma unroll
        for (int j = 0; j < 32; ++j) {
            hv2 f, r;
            f.x = (__fp16)Wsel[(2 * j) * NCOL + col];
            f.y = (__fp16)Wsel[(2 * j + 1) * NCOL + col];
            r.x = (__fp16)Usel[(2 * j) * NCOL + col];
            r.y = (__fp16)Usel[(2 * j + 1) * NCOL + col];
            wF[j][gg] = f;
            wR[j][gg] = r;
        }
        biasv[gg] = bsel[col];
    }

    // zero packed-h buffers: exactly 192 u32
    ((unsigned int*)lhp)[tid] = 0u;

    // x: wave 0, lanes<32 stream pair (x[t][2j], x[t][2j+1]) as float2
    const float2* x2 = (const float2*)(x + (size_t)b * SEQT * FEAT);
    float2 xrA = {0.f, 0.f}, xrB = {0.f, 0.f};
    if (g == 0 && u < 32) {
        xrA = x2[0 * 32 + u];    // x(0)
        xrB = x2[1 * 32 + u];    // x(1)
    }
    __syncthreads();

    float c = 0.f, h = 0.f;
    unsigned int rpk = 0u;      // own h(t-1) packed pair (lane j<32 holds pair j)

#define TICK(TK, XR)                                                          \
    {                                                                         \
        const int p_ = (TK) & 1;                                              \
        const int t_ = (TK) - g;                                              \
        const float2 xcur = XR;                                               \
        if (g == 0 && u < 32) {     /* refill with x(TK+2), in flight 2 ticks */\
            int tn = (TK) + 2; if (tn > SEQT - 1) tn = SEQT - 1;              \
            XR = x2[(size_t)tn * 32 + u];                                     \
        }                                                                     \
        if (t_ >= 0 && t_ < SEQT) {                                           \
            unsigned int ffpk;                                                \
            if (g == 0) ffpk = __builtin_bit_cast(unsigned int,               \
                                                  cvtpk_(xcur.x, xcur.y));    \
            else        ffpk = lhp[g - 1][p_ ^ 1][j32];   /* 1 ds_read_b32 */ \
            float a0A = 0.f, a0B = 0.f, a1A = 0.f, a1B = 0.f;                 \
            float a2A = 0.f, a2B = 0.f, a3A = 0.f, a3B = 0.f;                 \
            _Pragma("unroll")                                                 \
            for (int j = 0; j < 32; j += 2) {                                 \
                hv2 r0 = __builtin_bit_cast(hv2, rlane_(rpk, j));             \
                hv2 r1 = __builtin_bit_cast(hv2, rlane_(rpk, j + 1));         \
                a0A = fdot2_(r0, wR[j][0], a0A);                              \
                a1A = fdot2_(r0, wR[j][1], a1A);                              \
                a2A = fdot2_(r0, wR[j][2], a2A);                              \
                a3A = fdot2_(r0, wR[j][3], a3A);                              \
                a0B = fdot2_(r1, wR[j + 1][0], a0B);                          \
                a1B = fdot2_(r1, wR[j + 1][1], a1B);                          \
                a2B = fdot2_(r1, wR[j + 1][2], a2B);                          \
                a3B = fdot2_(r1, wR[j + 1][3], a3B);                          \
            }                                                                 \
            _Pragma("unroll")                                                 \
            for (int j = 0; j < 32; j += 2) {                                 \
                hv2 f0 = __builtin_bit_cast(hv2, rlane_(ffpk, j));            \
                hv2 f1 = __builtin_bit_cast(hv2, rlane_(ffpk, j + 1));        \
                a0A = fdot2_(f0, wF[j][0], a0A);                              \
                a1A = fdot2_(f0, wF[j][1], a1A);                              \
                a2A = fdot2_(f0, wF[j][2], a2A);                              \
                a3A = fdot2_(f0, wF[j][3], a3A);                              \
                a0B = fdot2_(f1, wF[j + 1][0], a0B);                          \
                a1B = fdot2_(f1, wF[j + 1][1], a1B);                          \
                a2B = fdot2_(f1, wF[j + 1][2], a2B);                          \
                a3B = fdot2_(f1, wF[j + 1][3], a3B);                          \
            }                                                                 \
            const float zi = a0A + a0B + biasv[0];                            \
            const float zf = a1A + a1B + biasv[1];                            \
            const float zg = a2A + a2B + biasv[2];                            \
            const float zo = a3A + a3B + biasv[3];                            \
            const float ig = sig_(zi), fg = sig_(zf);                         \
            const float gv = tanh_(zg), og = sig_(zo);                        \
            c = fg * c + ig * gv;                                             \
            h = og * tanh_(c);                                                \
            const float h0 = bperm_(j32 * 8,     h);   /* h[2j]   */          \
            const float h1 = bperm_(j32 * 8 + 4, h);   /* h[2j+1] */          \
            rpk = __builtin_bit_cast(unsigned int, cvtpk_(h0, h1));           \
            if (u < 32) lhp[g][p_][u] = rpk;          /* FF handoff */        \
            if (g == 2 && t_ == SEQT - 1) lh2f[u] = h;                        \
        }                                                                     \
        asm volatile("s_waitcnt lgkmcnt(0)\n\ts_barrier" ::: "memory");       \
    }

    for (int tk = 0; tk < SEQT + 2; tk += 2) {
        TICK(tk,     xrA)
        TICK(tk + 1, xrB)
    }
#undef TICK

    __syncthreads();

    // ---- dense head on final h2 (f32) ----
    if (tid < UNITS) {
        float a = bfv[tid];
#pragma unroll
        for (int k = 0; k < UNITS; ++k) a += lh2f[k] * Wf[k * 64 + tid];
        lact[tid] = fmaxf(a, 0.f);
    }
    __syncthreads();
    if (tid < OUTD) {
        float a = bov[tid];
#pragma unroll
        for (int k = 0; k < UNITS; ++k) a += lact[k] * Wo[k * OUTD + tid];
        out[b * OUTD + tid] = a;
    }
}

extern "C" void kernel_launch(void* const* d_in, const int* in_sizes, int n_in,
                              void* d_out, int out_size, void* d_ws, size_t ws_size,
                              hipStream_t stream) {
    const float* x   = (const float*)d_in[0];
    const float* W0  = (const float*)d_in[1];
    const float* U0  = (const float*)d_in[2];
    const float* b0  = (const float*)d_in[3];
    const float* W1  = (const float*)d_in[4];
    const float* U1  = (const float*)d_in[5];
    const float* b1  = (const float*)d_in[6];
    const float* Wf  = (const float*)d_in[7];
    const float* bfv = (const float*)d_in[8];
    const float* Wo  = (const float*)d_in[9];
    const float* bov = (const float*)d_in[10];
    float* out = (float*)d_out;

    lstm3_w3<<<BATCHN, 192, 0, stream>>>(x, W0, U0, b0, W1, U1, b1,
                                         Wf, bfv, Wo, bov, out);
}

// Round 15
// 1884.939 us; speedup vs baseline: 1.3418x; 1.0215x over previous
//
#include <hip/hip_runtime.h>

#define BATCHN 128
#define SEQT   2048
#define FEAT   64
#define UNITS  64
#define NCOL   256   // 4*UNITS gate columns
#define OUTD   6

typedef __fp16 hv2 __attribute__((ext_vector_type(2)));

__device__ __forceinline__ float fast_exp2(float x) {
#if __has_builtin(__builtin_amdgcn_exp2f)
    return __builtin_amdgcn_exp2f(x);
#else
    return exp2f(x);
#endif
}
__device__ __forceinline__ float fast_rcp(float x) {
#if __has_builtin(__builtin_amdgcn_rcpf)
    return __builtin_amdgcn_rcpf(x);
#else
    return 1.0f / x;
#endif
}
__device__ __forceinline__ float sig_(float x) {
    return fast_rcp(1.0f + fast_exp2(-1.4426950408889634f * x));
}
// tanh(x) = 2/(1+e^{-2x}) - 1
__device__ __forceinline__ float tanh_(float x) {
    float e = fast_exp2(-2.8853900817779268f * x);   // e^{-2x}
    return fmaf(2.0f, fast_rcp(1.0f + e), -1.0f);
}

// 2xf16 MAC with f32 accumulate (v_dot2_f32_f16)
__device__ __forceinline__ float fdot2_(hv2 a, hv2 b, float c) {
#if __has_builtin(__builtin_amdgcn_fdot2)
    return __builtin_amdgcn_fdot2(a, b, c, false);
#else
    return fmaf((float)a.x, (float)b.x, fmaf((float)a.y, (float)b.y, c));
#endif
}
__device__ __forceinline__ hv2 cvtpk_(float a, float b) {
    return __builtin_amdgcn_cvt_pkrtz(a, b);
}
// wave-uniform broadcast of lane l's u32 (compile-time l)
__device__ __forceinline__ unsigned int rlane_(unsigned int v, int l) {
    return (unsigned int)__builtin_amdgcn_readlane((int)v, l);
}
// pull f32 from lane (byteaddr/4)
__device__ __forceinline__ float bperm_(int byteaddr, float v) {
    return __builtin_bit_cast(float,
        __builtin_amdgcn_ds_bpermute(byteaddr, __builtin_bit_cast(int, v)));
}

// 6 waves = (layer g, role r): FF_g holds W only, REC_g holds U only
// (128 weight VGPRs each -> no spill). Lane u owns unit u's 4 gate cols over
// full K=64: dot completes in-lane. Operands broadcast via v_readlane of
// packed f16x2. REC keeps h as register state (2x ds_bpermute repack).
// Handoffs per tick: FF->REC one float4 (z_ff) via LDS; REC_g -> FF_{g+1}
// 32 packed u32 via LDS. 6-stage skew (alpha=2g+r), 1 barrier/tick.
__global__ __launch_bounds__(384, 2)
void lstm3_ffrec(const float* __restrict__ x,
                 const float* __restrict__ W0, const float* __restrict__ U0,
                 const float* __restrict__ b0,
                 const float* __restrict__ W1, const float* __restrict__ U1,
                 const float* __restrict__ b1,
                 const float* __restrict__ Wf, const float* __restrict__ bfv,
                 const float* __restrict__ Wo, const float* __restrict__ bov,
                 float* __restrict__ out)
{
    const int b   = blockIdx.x;
    const int tid = threadIdx.x;   // 0..383
    const int wid = tid >> 6;      // 0..5
    const int g   = wid >> 1;      // layer 0,1,2
    const int r   = wid & 1;       // 0=FF (W), 1=REC (U + activations)
    const int u   = tid & 63;      // unit/lane
    const int j32 = u & 31;

    __shared__ unsigned int lhp[3][2][32];          // packed h pairs [layer][step-parity]
    __shared__ __align__(16) float lzf[3][2][UNITS][4];  // z_ff float4 [layer][step-parity]
    __shared__ float lh2f[UNITS];
    __shared__ float lact[UNITS];

    // ---- weights: 4 cols x 64 k of ONE matrix, f16 k-pairs (128 VGPRs) ----
    const float* M = (g == 0) ? ((r == 0) ? W0 : U0) : ((r == 0) ? W1 : U1);
    const float* bsel = (g == 0) ? b0 : b1;

    hv2 wM[32][4];
    float biasv[4];
#pragma unroll
    for (int gg = 0; gg < 4; ++gg) {
        const int col = (gg << 6) + u;
#pragma unroll
        for (int j = 0; j < 32; ++j) {
            hv2 w;
            w.x = (__fp16)M[(2 * j) * NCOL + col];
            w.y = (__fp16)M[(2 * j + 1) * NCOL + col];
            wM[j][gg] = w;
        }
        biasv[gg] = bsel[col];   // only FF uses it (acc init)
    }

    // zero handoff buffers
    if (tid < 192) ((unsigned int*)lhp)[tid] = 0u;
    for (int i = tid; i < 3 * 2 * UNITS * 4; i += 384) ((float*)lzf)[i] = 0.f;

    // x: wave 0 (FF_0), lanes<32 stream pairs (x[t][2u], x[t][2u+1])
    const float2* x2 = (const float2*)(x + (size_t)b * SEQT * FEAT);
    float2 xrA = {0.f, 0.f}, xrB = {0.f, 0.f};
    if (wid == 0 && u < 32) {
        xrA = x2[0 * 32 + u];    // x(0)
        xrB = x2[1 * 32 + u];    // x(1)
    }
    __syncthreads();

    const int alpha = 2 * g + r;
    float c = 0.f, h = 0.f;
    unsigned int rpk = 0u;       // REC: own h(t-1) packed (lane j<32 = pair j)

#define TICK(TK, XR)                                                          \
    {                                                                         \
        const int t_ = (TK) - alpha;                                          \
        const float2 xcur = XR;                                               \
        if (wid == 0 && u < 32) {   /* refill with x(TK+2) */                 \
            int tn = (TK) + 2; if (tn > SEQT - 1) tn = SEQT - 1;              \
            XR = x2[(size_t)tn * 32 + u];                                     \
        }                                                                     \
        if (t_ >= 0 && t_ < SEQT) {                                           \
            const int p_ = t_ & 1;                                            \
            unsigned int srcpk;                                               \
            float4 zin = {0.f, 0.f, 0.f, 0.f};                                \
            if (r == 0) {                                                     \
                srcpk = (g == 0) ? __builtin_bit_cast(unsigned int,           \
                                                      cvtpk_(xcur.x, xcur.y)) \
                                 : lhp[g - 1][p_][j32];    /* 1 b32 */        \
            } else {                                                          \
                srcpk = rpk;                                                  \
                zin = *(const float4*)&lzf[g][p_][u][0];   /* 1 b128 */       \
            }                                                                 \
            float aA0, aA1, aA2, aA3;                                         \
            if (r == 0) { aA0 = biasv[0]; aA1 = biasv[1];                     \
                          aA2 = biasv[2]; aA3 = biasv[3]; }                   \
            else        { aA0 = zin.x; aA1 = zin.y;                           \
                          aA2 = zin.z; aA3 = zin.w; }                         \
            float aB0 = 0.f, aB1 = 0.f, aB2 = 0.f, aB3 = 0.f;                 \
            _Pragma("unroll")                                                 \
            for (int j = 0; j < 32; j += 2) {                                 \
                hv2 p0 = __builtin_bit_cast(hv2, rlane_(srcpk, j));           \
                hv2 p1 = __builtin_bit_cast(hv2, rlane_(srcpk, j + 1));       \
                aA0 = fdot2_(p0, wM[j][0], aA0);                              \
                aA1 = fdot2_(p0, wM[j][1], aA1);                              \
                aA2 = fdot2_(p0, wM[j][2], aA2);                              \
                aA3 = fdot2_(p0, wM[j][3], aA3);                              \
                aB0 = fdot2_(p1, wM[j + 1][0], aB0);                          \
                aB1 = fdot2_(p1, wM[j + 1][1], aB1);                          \
                aB2 = fdot2_(p1, wM[j + 1][2], aB2);                          \
                aB3 = fdot2_(p1, wM[j + 1][3], aB3);                          \
            }                                                                 \
            if (r == 0) {            /* publish z_ff(t) */                    \
                float4 z4 = {aA0 + aB0, aA1 + aB1, aA2 + aB2, aA3 + aB3};     \
                *(float4*)&lzf[g][p_][u][0] = z4;                             \
            } else {                 /* gates + state update */               \
                const float zi = aA0 + aB0, zf = aA1 + aB1;                   \
                const float zg = aA2 + aB2, zo = aA3 + aB3;                   \
                const float ig = sig_(zi), fg = sig_(zf);                     \
                const float gv = tanh_(zg), og = sig_(zo);                    \
                c = fg * c + ig * gv;                                         \
                h = og * tanh_(c);                                            \
                const float h0 = bperm_(j32 * 8,     h);                      \
                const float h1 = bperm_(j32 * 8 + 4, h);                      \
                rpk = __builtin_bit_cast(unsigned int, cvtpk_(h0, h1));       \
                if (u < 32) lhp[g][p_][u] = rpk;                              \
                if (g == 2 && t_ == SEQT - 1) lh2f[u] = h;                    \
            }                                                                 \
        }                                                                     \
        asm volatile("s_waitcnt lgkmcnt(0)\n\ts_barrier" ::: "memory");       \
    }

    for (int tk = 0; tk < SEQT + 6; tk += 2) {
        TICK(tk,     xrA)
        TICK(tk + 1, xrB)
    }
#undef TICK

    __syncthreads();

    // ---- dense head on final h2 (f32) ----
    if (tid < UNITS) {
        float a = bfv[tid];
#pragma unroll
        for (int k = 0; k < UNITS; ++k) a += lh2f[k] * Wf[k * 64 + tid];
        lact[tid] = fmaxf(a, 0.f);
    }
    __syncthreads();
    if (tid < OUTD) {
        float a = bov[tid];
#pragma unroll
        for (int k = 0; k < UNITS; ++k) a += lact[k] * Wo[k * OUTD + tid];
        out[b * OUTD + tid] = a;
    }
}

extern "C" void kernel_launch(void* const* d_in, const int* in_sizes, int n_in,
                              void* d_out, int out_size, void* d_ws, size_t ws_size,
                              hipStream_t stream) {
    const float* x   = (const float*)d_in[0];
    const float* W0  = (const float*)d_in[1];
    const float* U0  = (const float*)d_in[2];
    const float* b0  = (const float*)d_in[3];
    const float* W1  = (const float*)d_in[4];
    const float* U1  = (const float*)d_in[5];
    const float* b1  = (const float*)d_in[6];
    const float* Wf  = (const float*)d_in[7];
    const float* bfv = (const float*)d_in[8];
    const float* Wo  = (const float*)d_in[9];
    const float* bov = (const float*)d_in[10];
    float* out = (float*)d_out;

    lstm3_ffrec<<<BATCHN, 384, 0, stream>>>(x, W0, U0, b0, W1, U1, b1,
                                            Wf, bfv, Wo, bov, out);
}